// Round 12
// baseline (239.453 us; speedup 1.0000x reference)
//
#include <hip/hip_runtime.h>

// Problem constants (B=2, S=4096, D=512, H=8, Dh=64). f32 I/O, bf16 MFMA inside.
#define MTOT 8192  // B*S

typedef __attribute__((ext_vector_type(8))) short bf16x8;
typedef __attribute__((ext_vector_type(4))) float f32x4;
typedef __attribute__((ext_vector_type(16))) float f32x16;

// Native exp2 via builtin ONLY (round-2 lesson: inline-asm v_exp_f32 bypasses
// the compiler's MFMA/trans hazard handling -> silent corruption).
#if __has_builtin(__builtin_amdgcn_exp2f)
#define EXP2F __builtin_amdgcn_exp2f
#else
#define EXP2F exp2f
#endif

#define SC 0.18033688011112042f  // (1/8) * log2(e), folded into K
#define LDP 72                   // LDS row stride (el) for old gemm / attn K tile
#define CTS 136                  // epilogue C-tile stride (el), V-transpose
#define CTQ 72                   // epilogue C-tile stride (el), Q/K direct

// Truncation f32->bf16 (1 VALU). Error budget ample (0.031 vs 0.099 thresh).
static __device__ __forceinline__ unsigned short tb(float f) {
  union { float f; unsigned int i; } x;
  x.f = f;
  return (unsigned short)(x.i >> 16);
}
static __device__ __forceinline__ unsigned int pkt(float a, float b) {
  union { float f; unsigned int i; } xa, xb;
  xa.f = a; xb.f = b;
  return (xa.i >> 16) | (xb.i & 0xFFFF0000u);
}
static __device__ __forceinline__ bf16x8 ld8f32_bf16(const float* __restrict__ p) {
  f32x4 lo = *(const f32x4*)p;
  f32x4 hi = *(const f32x4*)(p + 4);
  union { unsigned int u[4]; bf16x8 v; } r;
  r.u[0] = pkt(lo[0], lo[1]);
  r.u[1] = pkt(lo[2], lo[3]);
  r.u[2] = pkt(hi[0], hi[1]);
  r.u[3] = pkt(hi[2], hi[3]);
  return r.v;
}

// Async global->LDS, 16B per lane (dest = uniform base + lane*16).
static __device__ __forceinline__ void stage16(const unsigned short* g,
                                               unsigned short* l, int lane) {
#if __has_builtin(__builtin_amdgcn_global_load_lds)
  __builtin_amdgcn_global_load_lds(
      (const __attribute__((address_space(1))) void*)g,
      (__attribute__((address_space(3))) void*)l, 16, 0, 0);
#else
  *(uint4*)(l + lane * 8) = *(const uint4*)g;
#endif
}

// ---------------------------------------------------------------------------
// Kernel 0 (fast path): f32 -> bf16. dst = [Abf 8192x512][Wbf 1536x512]
// (Wbf rows 0..1023 = Wc, 1024..1535 = Wv). dst lives in the OUTPUT buffer
// (dead until attn's final store; stream order serializes the hazard).
// ---------------------------------------------------------------------------
__global__ __launch_bounds__(256) void convert_bf16(
    const float* __restrict__ mf,
    const float* __restrict__ Wc,
    const float* __restrict__ Wv,
    unsigned short* __restrict__ dst)
{
  const size_t NA = (size_t)MTOT * 512;
  const size_t NW = (size_t)1536 * 512;
  const size_t total = (NA + NW) / 8;
  for (size_t u = (size_t)blockIdx.x * blockDim.x + threadIdx.x; u < total;
       u += (size_t)gridDim.x * blockDim.x) {
    const size_t el = u * 8;
    const float* src;
    if (el < NA) {
      src = mf + el;
    } else {
      const size_t e2 = el - NA;
      src = (e2 < (size_t)1024 * 512) ? (Wc + e2) : (Wv + (e2 - (size_t)1024 * 512));
    }
    f32x4 lo = *(const f32x4*)src;
    f32x4 hi = *(const f32x4*)(src + 4);
    uint4 pk;
    pk.x = pkt(lo[0], lo[1]); pk.y = pkt(lo[2], lo[3]);
    pk.z = pkt(hi[0], hi[1]); pk.w = pkt(hi[2], hi[3]);
    *(uint4*)(dst + el) = pk;
  }
}

// ---------------------------------------------------------------------------
// Kernel 1 (fast path): projection GEMM (round-8 verified). 128x64 tiles ->
// 1536 blocks (6/CU by 24KB LDS), acc[4][2]=32 AGPR. DMA staging: linear LDS
// dest + XOR-pre-swizzled per-lane GLOBAL source; reads use chunk^(n&7).
// XCD-chunked block swizzle (8 tm per XCD).
// Columns (tn of 24): 0-7 Q (+bc), 8-15 V (+bc, transposed), 16-23 K (+bv,*SC).
// ---------------------------------------------------------------------------
__global__ __launch_bounds__(256) void gemm_fast(
    const unsigned short* __restrict__ Abf,
    const unsigned short* __restrict__ Wbf,
    const float* __restrict__ bc,
    const float* __restrict__ bv,
    unsigned short* __restrict__ ws)
{
  const int cpx = (int)gridDim.x >> 3;  // 192 blocks per XCD chunk
  const int bid = ((int)blockIdx.x & 7) * cpx + ((int)blockIdx.x >> 3);
  const int tn = bid % 24, tm = bid / 24;
  const int w = threadIdx.x >> 6, lane = threadIdx.x & 63;
  const int n = lane & 15, q = lane >> 4;

  __shared__ alignas(16) unsigned short smem[128 * 64 + 64 * 64];  // As|Bs 24KB; Ct overlay
  unsigned short* As = smem;              // [128][64] linear (DMA dest)
  unsigned short* Bs = smem + 128 * 64;   // [64][64] linear

  f32x4 acc[4][2] = {};
  const int rowA0 = tm * 128, colB0 = tn * 64;
  const int lrow = lane >> 3;                       // 0..7 row in 8-row group
  const int sw = ((lane & 7) ^ lrow) * 8;           // XOR-swizzled source chunk
  const unsigned short* gA = Abf + (size_t)(rowA0 + w * 32 + lrow) * 512 + sw;
  const unsigned short* gB = Wbf + (size_t)(colB0 + w * 16 + lrow) * 512 + sw;

  for (int kc = 0; kc < 512; kc += 64) {
    // A: wave w rows [w*32, w*32+32); B: rows [w*16, w*16+16)
#pragma unroll
    for (int rr = 0; rr < 4; ++rr)
      stage16(gA + (size_t)rr * 8 * 512 + kc, As + (w * 32 + rr * 8) * 64, lane);
#pragma unroll
    for (int rr = 0; rr < 2; ++rr)
      stage16(gB + (size_t)rr * 8 * 512 + kc, Bs + (w * 16 + rr * 8) * 64, lane);
    __syncthreads();   // vmcnt(0) drain + barrier: tiles valid
#pragma unroll
    for (int ks = 0; ks < 2; ++ks) {
      const int ch = ((ks * 4 + q) ^ (n & 7)) * 8;  // swizzled read chunk
      bf16x8 a[4], b[2];
#pragma unroll
      for (int si = 0; si < 4; ++si)
        a[si] = *(const bf16x8*)(&As[((w >> 1) * 64 + si * 16 + n) * 64 + ch]);
#pragma unroll
      for (int sj = 0; sj < 2; ++sj)
        b[sj] = *(const bf16x8*)(&Bs[((w & 1) * 32 + sj * 16 + n) * 64 + ch]);
#pragma unroll
      for (int si = 0; si < 4; ++si)
#pragma unroll
        for (int sj = 0; sj < 2; ++sj)
          acc[si][sj] = __builtin_amdgcn_mfma_f32_16x16x32_bf16(a[si], b[sj], acc[si][sj], 0, 0, 0);
    }
    __syncthreads();   // all reads done before next stage overwrites
  }

  // ---- epilogue: LDS transpose (Ct overlays As/Bs) then coalesced stores ----
  unsigned short* Ct = smem;
  const bool isV = (tn >= 8 && tn < 16);
  const int rl0 = (w >> 1) * 64, cl0 = (w & 1) * 32;

  if (!isV) {
    const bool isK = (tn >= 16);
#pragma unroll
    for (int sj = 0; sj < 2; ++sj) {
      const int c = colB0 + cl0 + sj * 16 + n;      // full output column
      const float bias = isK ? bv[c - 1024] : bc[c];
#pragma unroll
      for (int si = 0; si < 4; ++si)
#pragma unroll
        for (int r = 0; r < 4; ++r) {
          float v = acc[si][sj][r] + bias;
          if (isK) v *= SC;
          Ct[(rl0 + si * 16 + q * 4 + r) * CTQ + cl0 + sj * 16 + n] = tb(v);
        }
    }
  } else {
#pragma unroll
    for (int sj = 0; sj < 2; ++sj) {
      const float bias = bc[colB0 + cl0 + sj * 16 + n];
#pragma unroll
      for (int si = 0; si < 4; ++si) {
        uint2 pk;
        pk.x = pkt(acc[si][sj][0] + bias, acc[si][sj][1] + bias);
        pk.y = pkt(acc[si][sj][2] + bias, acc[si][sj][3] + bias);
        *(uint2*)(&Ct[(cl0 + sj * 16 + n) * CTS + rl0 + si * 16 + q * 4]) = pk;
      }
    }
  }
  __syncthreads();

  if (!isV) {
    // Ct is [128][CTQ=72]; tile 128 rows x 64 cols
    const int rk = threadIdx.x & 7, rr2 = threadIdx.x >> 3;
#pragma unroll
    for (int rp = 0; rp < 4; ++rp) {
      const int row = rp * 32 + rr2;
      const int col = rk * 8;
      bf16x8 v = *(const bf16x8*)(&Ct[row * CTQ + col]);
      const int srow = rowA0 + row;
      const int bb = srow >> 12, ss = srow & 4095;
      const int cg = colB0 + col;
      const int cl = (cg >= 1024) ? (cg - 1024) : cg;   // K maps to [0,512)
      const int hh = cl >> 6, dh0 = cl & 63;
      unsigned short* base = (cg >= 1024) ? (ws + (size_t)2 * MTOT * 512) : ws;
      *(bf16x8*)(base + ((size_t)((bb * 8 + hh) * 4096 + ss)) * 64 + dh0) = v;
    }
  } else {
    // Ct is [64][CTS=136]; transposed tile 64 ch-rows x 128 s-cols
    const int rk = threadIdx.x & 15, rr2 = threadIdx.x >> 4;
#pragma unroll
    for (int rp = 0; rp < 4; ++rp) {
      const int row = rp * 16 + rr2;
      const int col = rk * 8;
      bf16x8 v = *(const bf16x8*)(&Ct[row * CTS + col]);
      const int cv = (tn - 8) * 64 + row;               // channel [0,512)
      const int hh = cv >> 6, dh0 = cv & 63;
      const int sg = rowA0 + col;
      const int bb = sg >> 12, ss = sg & 4095;
      *(bf16x8*)(ws + (size_t)MTOT * 512 +
                 ((size_t)((bb * 8 + hh) * 64 + dh0)) * 4096 + ss) = v;
    }
  }
}

// ---------------------------------------------------------------------------
// Kernel 1 (fallback, ws-limited): original VALU-staged projection GEMM.
// ---------------------------------------------------------------------------
__global__ __launch_bounds__(256) void gemm_qvk(
    const float* __restrict__ mf,
    const float* __restrict__ Wc,
    const float* __restrict__ bc,
    const float* __restrict__ Wv,
    const float* __restrict__ bv,
    unsigned short* __restrict__ ws,
    int nct)
{
  const int cpx = (int)gridDim.x >> 3;
  const int bid = ((int)blockIdx.x & 7) * cpx + ((int)blockIdx.x >> 3);
  const int tn = bid % nct, tm = bid / nct;
  const int w = threadIdx.x >> 6, lane = threadIdx.x & 63;
  const int n = lane & 15, q = lane >> 4;

  __shared__ alignas(16) unsigned short smem[2 * 128 * LDP];
  unsigned short* As = smem;
  unsigned short* Bs = smem + 128 * LDP;

  f32x4 acc[4][4] = {};
  const int rowA0 = tm * 128, colB0 = tn * 128;
  const int sr = threadIdx.x >> 4;
  const int sc = (threadIdx.x & 15) * 4;

  for (int kc = 0; kc < 512; kc += 64) {
    __syncthreads();
#pragma unroll
    for (int rr = 0; rr < 8; ++rr) {
      const int row = rr * 16 + sr;
      f32x4 av = *(const f32x4*)(mf + (size_t)(rowA0 + row) * 512 + kc + sc);
      uint2 ap; ap.x = pkt(av[0], av[1]); ap.y = pkt(av[2], av[3]);
      *(uint2*)(&As[row * LDP + sc]) = ap;
      const int c = colB0 + row;
      const float* bsrc = (c < 1024) ? (Wc + (size_t)c * 512)
                                     : (Wv + (size_t)(c - 1024) * 512);
      f32x4 bvx = *(const f32x4*)(bsrc + kc + sc);
      uint2 bp; bp.x = pkt(bvx[0], bvx[1]); bp.y = pkt(bvx[2], bvx[3]);
      *(uint2*)(&Bs[row * LDP + sc]) = bp;
    }
    __syncthreads();
#pragma unroll
    for (int ks = 0; ks < 2; ++ks) {
      bf16x8 a[4], b[4];
#pragma unroll
      for (int si = 0; si < 4; ++si)
        a[si] = *(const bf16x8*)(&As[((w >> 1) * 64 + si * 16 + n) * LDP + ks * 32 + q * 8]);
#pragma unroll
      for (int sj = 0; sj < 4; ++sj)
        b[sj] = *(const bf16x8*)(&Bs[((w & 1) * 64 + sj * 16 + n) * LDP + ks * 32 + q * 8]);
#pragma unroll
      for (int si = 0; si < 4; ++si)
#pragma unroll
        for (int sj = 0; sj < 4; ++sj)
          acc[si][sj] = __builtin_amdgcn_mfma_f32_16x16x32_bf16(a[si], b[sj], acc[si][sj], 0, 0, 0);
    }
  }

  __syncthreads();
  unsigned short* Ct = smem;
  const bool isV = (tn >= 4 && tn < 8);
  const int rl0 = (w >> 1) * 64, cl0 = (w & 1) * 64;

  if (!isV) {
    const bool isK = (tn >= 8);
#pragma unroll
    for (int sj = 0; sj < 4; ++sj) {
      const int c = colB0 + cl0 + sj * 16 + n;
      const float bias = isK ? bv[c - 1024] : bc[c];
#pragma unroll
      for (int si = 0; si < 4; ++si)
#pragma unroll
        for (int r = 0; r < 4; ++r) {
          float v = acc[si][sj][r] + bias;
          if (isK) v *= SC;
          Ct[(rl0 + si * 16 + q * 4 + r) * CTS + cl0 + sj * 16 + n] = tb(v);
        }
    }
  } else {
#pragma unroll
    for (int sj = 0; sj < 4; ++sj) {
      const float bias = bc[colB0 + cl0 + sj * 16 + n];
#pragma unroll
      for (int si = 0; si < 4; ++si) {
        uint2 pk;
        pk.x = pkt(acc[si][sj][0] + bias, acc[si][sj][1] + bias);
        pk.y = pkt(acc[si][sj][2] + bias, acc[si][sj][3] + bias);
        *(uint2*)(&Ct[(cl0 + sj * 16 + n) * CTS + rl0 + si * 16 + q * 4]) = pk;
      }
    }
  }
  __syncthreads();

  const int rk = threadIdx.x & 7, rr2 = threadIdx.x >> 3;
#pragma unroll
  for (int rp = 0; rp < 4; ++rp) {
    const int row = rp * 32 + rr2;
#pragma unroll
    for (int ch = 0; ch < 2; ++ch) {
      const int col = ch * 64 + rk * 8;
      bf16x8 v = *(const bf16x8*)(&Ct[row * CTS + col]);
      if (!isV) {
        const int srow = rowA0 + row;
        const int bb = srow >> 12, ss = srow & 4095;
        const int cg = colB0 + col;
        const int cl = (cg >= 1024) ? (cg - 1024) : cg;
        const int hh = cl >> 6, dh0 = cl & 63;
        unsigned short* base = (cg >= 1024) ? (ws + (size_t)2 * MTOT * 512) : ws;
        *(bf16x8*)(base + ((size_t)((bb * 8 + hh) * 4096 + ss)) * 64 + dh0) = v;
      } else {
        const int cv = (tn - 4) * 128 + row;
        const int hh = cv >> 6, dh0 = cv & 63;
        const int sg = rowA0 + col;
        const int bb = sg >> 12, ss = sg & 4095;
        *(bf16x8*)(ws + (size_t)MTOT * 512 +
                   ((size_t)((bb * 8 + hh) * 64 + dh0)) * 4096 + ss) = v;
      }
    }
  }
}

// ---------------------------------------------------------------------------
// Kernel 2: flash attention, 32x32 MFMA restructure (round 12).
// Why: 16x16 structure needed an LDS P round-trip purely to transpose
// S[j][i] -> P[i][j] between QK and PV; 6 scheduling attempts at hiding its
// latency were null. With 32x32x16 and QK computed as mfma(A=Q, B=K), the
// D-layout (col=lane&31 -> i, row=(r&3)+8(r>>2)+4(lane>>5) -> j) puts i
// lane-resident EXACTLY as PV's A-operand requires (A row = lane&31). Only
// the partner half's j-values are missing: 4 shfl_xor(32) per score block
// (pre-selected messages) + 16 pkt replace all P stores/drains/reads.
// Also: 32x32x16 costs ~17% fewer matrix-pipe cycles than 2x 16x16x32.
//  - block = 2 waves, 64 i-rows (two 32-i blocks), waves split j (2048 each),
//    32-wide j tiles, 64 iters; exact f32 cross-wave merge via LDS.
//  - registers: aK 32 + bq 16 + bvv 16 + scores 32 + pack/exchange ~24
//    + o 64 AGPR ~= 175 total -> still 2 waves/SIMD (do NOT force more; r5).
// ---------------------------------------------------------------------------
template <bool KWS>
__global__ __launch_bounds__(128, 2) void attn_kernel(
    const unsigned short* __restrict__ qvws,
    const float* __restrict__ mf,
    const float* __restrict__ Wv,
    const float* __restrict__ bv,
    float* __restrict__ out)
{
  const int bid = blockIdx.x;
  const int bh = ((bid & 7) << 1) | ((bid >> 3) & 1);  // XCD-local bh pairing
  const int ibt = bid >> 4;
  const int b_ = bh >> 3, h = bh & 7;
  const int w = threadIdx.x >> 6, lane = threadIdx.x & 63;
  const int lo = lane & 31, hi = lane >> 5;
  const int i0 = ibt * 64;

  __shared__ alignas(16) unsigned short Kt[64 * LDP];  // K tile (fallback path)
  __shared__ alignas(16) float mO[64 * 68];            // cross-wave o merge
  __shared__ float lbuf[2][64];

  const unsigned short* Qb = qvws + (size_t)(bh * 4096) * 64;
  const unsigned short* Vb = qvws + (size_t)MTOT * 512 + (size_t)(bh * 64) * 4096;

  // aK[ib][cf]: B-operand frags, K[i0+ib*32+lo][cf*16 + hi*8 + e].
  bf16x8 aK[2][4];
  if (KWS) {
    const unsigned short* Kb = qvws + (size_t)2 * MTOT * 512 + (size_t)(bh * 4096) * 64;
#pragma unroll
    for (int ib = 0; ib < 2; ++ib)
#pragma unroll
      for (int cf = 0; cf < 4; ++cf)
        aK[ib][cf] = *(const bf16x8*)(Kb + (size_t)(i0 + ib * 32 + lo) * 64 + cf * 16 + hi * 8);
  } else {
    // Fallback: compute K tile (64 rows) via 16x16 mfma (verified path),
    // stage rows in Kt, then load 32x32 B-frags from it.
    const int n = lane & 15, q = lane >> 4;
    f32x4 ka[2][4] = {};
    for (int kk = 0; kk < 512; kk += 32) {
      bf16x8 a0 = ld8f32_bf16(mf + (size_t)(b_ * 4096 + i0 + (2 * w + 0) * 16 + n) * 512 + kk + q * 8);
      bf16x8 a1 = ld8f32_bf16(mf + (size_t)(b_ * 4096 + i0 + (2 * w + 1) * 16 + n) * 512 + kk + q * 8);
#pragma unroll
      for (int t = 0; t < 4; ++t) {
        bf16x8 bw = ld8f32_bf16(Wv + (size_t)(h * 64 + t * 16 + n) * 512 + kk + q * 8);
        ka[0][t] = __builtin_amdgcn_mfma_f32_16x16x32_bf16(a0, bw, ka[0][t], 0, 0, 0);
        ka[1][t] = __builtin_amdgcn_mfma_f32_16x16x32_bf16(a1, bw, ka[1][t], 0, 0, 0);
      }
    }
#pragma unroll
    for (int sl = 0; sl < 2; ++sl)
#pragma unroll
      for (int t = 0; t < 4; ++t) {
        const float bias = bv[h * 64 + t * 16 + n];
#pragma unroll
        for (int r = 0; r < 4; ++r)
          Kt[((2 * w + sl) * 16 + q * 4 + r) * LDP + t * 16 + n] =
              tb((ka[sl][t][r] + bias) * SC);
      }
    __syncthreads();
#pragma unroll
    for (int ib = 0; ib < 2; ++ib)
#pragma unroll
      for (int cf = 0; cf < 4; ++cf)
        aK[ib][cf] = *(const bf16x8*)(&Kt[(ib * 32 + lo) * LDP + cf * 16 + hi * 8]);
  }

  f32x16 o[2][2] = {};        // o[ib][df]: O[i0+ib*32+iloc(r)][df*32+lo]
  float lsc[2] = {0.0f, 0.0f};
  const int jbase = w * 2048;

  // Per-lane base pointers. Q: row j+lo, cols cf*16+hi*8. V^T: row df*32+lo,
  // cols j + kf*16 + hi*8.
  const unsigned short* qrow = Qb + (size_t)lo * 64 + hi * 8;
  const unsigned short* vr0 = Vb + (size_t)(0 * 32 + lo) * 4096 + hi * 8;
  const unsigned short* vr1 = Vb + (size_t)(1 * 32 + lo) * 4096 + hi * 8;

  bf16x8 bq[4], bvv[2][2];
#pragma unroll
  for (int cf = 0; cf < 4; ++cf)
    bq[cf] = *(const bf16x8*)(qrow + (size_t)jbase * 64 + cf * 16);
#pragma unroll
  for (int kf = 0; kf < 2; ++kf) {
    bvv[0][kf] = *(const bf16x8*)(vr0 + jbase + kf * 16);
    bvv[1][kf] = *(const bf16x8*)(vr1 + jbase + kf * 16);
  }

  for (int it = 0; it < 64; ++it) {
    const int j1 = jbase + ((it + 1) & 63) * 32;  // next tile (wraps; redundant last)

    // QK: S[i = i0+ib*32+lo][j = jc + (r&3)+8(r>>2)+4hi], i lane-resident.
    f32x16 c0 = {}, c1 = {};
#pragma unroll
    for (int cf = 0; cf < 4; ++cf)
      c0 = __builtin_amdgcn_mfma_f32_32x32x16_bf16(bq[cf], aK[0][cf], c0, 0, 0, 0);
#pragma unroll
    for (int cf = 0; cf < 4; ++cf)
      c1 = __builtin_amdgcn_mfma_f32_32x32x16_bf16(bq[cf], aK[1][cf], c1, 0, 0, 0);

    // Prefetch next-iter Q (bq dead after QK issue).
#pragma unroll
    for (int cf = 0; cf < 4; ++cf)
      bq[cf] = *(const bf16x8*)(qrow + (size_t)j1 * 64 + cf * 16);

    // exp -> pack -> half-wave exchange -> PV, per i-block.
#pragma unroll
    for (int ib = 0; ib < 2; ++ib) {
      const f32x16 cc = ib ? c1 : c0;
      float e[16];
#pragma unroll
      for (int r = 0; r < 16; ++r) e[r] = EXP2F(cc[r]);
      float s = 0.0f;
#pragma unroll
      for (int r = 0; r < 16; ++r) s += e[r];
      lsc[ib] += s;

      unsigned int pk[8];
#pragma unroll
      for (int m = 0; m < 8; ++m) pk[m] = pkt(e[2 * m], e[2 * m + 1]);

      // Symmetric exchange: send exactly what the partner half needs.
      unsigned int rcv[4];
      rcv[0] = __shfl_xor(hi ? pk[0] : pk[2], 32, 64);
      rcv[1] = __shfl_xor(hi ? pk[1] : pk[3], 32, 64);
      rcv[2] = __shfl_xor(hi ? pk[4] : pk[6], 32, 64);
      rcv[3] = __shfl_xor(hi ? pk[5] : pk[7], 32, 64);

      union { uint4 u; bf16x8 v; } pa0, pa1;
      pa0.u = hi ? make_uint4(rcv[0], rcv[1], pk[2], pk[3])
                 : make_uint4(pk[0], pk[1], rcv[0], rcv[1]);
      pa1.u = hi ? make_uint4(rcv[2], rcv[3], pk[6], pk[7])
                 : make_uint4(pk[4], pk[5], rcv[2], rcv[3]);

      o[ib][0] = __builtin_amdgcn_mfma_f32_32x32x16_bf16(pa0.v, bvv[0][0], o[ib][0], 0, 0, 0);
      o[ib][1] = __builtin_amdgcn_mfma_f32_32x32x16_bf16(pa0.v, bvv[1][0], o[ib][1], 0, 0, 0);
      o[ib][0] = __builtin_amdgcn_mfma_f32_32x32x16_bf16(pa1.v, bvv[0][1], o[ib][0], 0, 0, 0);
      o[ib][1] = __builtin_amdgcn_mfma_f32_32x32x16_bf16(pa1.v, bvv[1][1], o[ib][1], 0, 0, 0);
    }

    // Prefetch next-iter V (bvv dead after PV issue).
#pragma unroll
    for (int kf = 0; kf < 2; ++kf) {
      bvv[0][kf] = *(const bf16x8*)(vr0 + j1 + kf * 16);
      bvv[1][kf] = *(const bf16x8*)(vr1 + j1 + kf * 16);
    }
  }

  // ---- merge: l via shfl + lbuf; o via LDS exchange (exact f32) ----
  float lw[2];
#pragma unroll
  for (int ib = 0; ib < 2; ++ib) {
    float v = lsc[ib];
    v += __shfl_xor(v, 32, 64);   // partner half holds complementary j
    lw[ib] = v;                   // wave total for i = ib*32 + lo
  }

  __syncthreads();                // fallback path: Kt reads done; sync before mO
  const int esub = 1 - w, ksub = w;   // wave exports i-block (1-w), keeps w
#pragma unroll
  for (int df = 0; df < 2; ++df)
#pragma unroll
    for (int r = 0; r < 16; ++r) {
      const int il = (r & 3) + 8 * (r >> 2) + 4 * hi;
      mO[(esub * 32 + il) * 68 + df * 32 + lo] = o[esub][df][r];
    }
  if (lane < 32) {
    lbuf[w][lane] = lw[0];
    lbuf[w][32 + lane] = lw[1];
  }
  __syncthreads();

  float li[16];
#pragma unroll
  for (int r = 0; r < 16; ++r) {
    const int il = ksub * 32 + (r & 3) + 8 * (r >> 2) + 4 * hi;
    li[r] = 1.0f / (lbuf[0][il] + lbuf[1][il]);
  }
#pragma unroll
  for (int df = 0; df < 2; ++df)
#pragma unroll
    for (int r = 0; r < 16; ++r) {
      const int il = (r & 3) + 8 * (r >> 2) + 4 * hi;
      const int i = i0 + ksub * 32 + il;
      const int d = df * 32 + lo;
      const size_t idx = (size_t)(b_ * 4096 + i) * 512 + h * 64 + d;
      out[idx] = (o[ksub][df][r] + mO[(ksub * 32 + il) * 68 + df * 32 + lo]) * li[r]
                 + mf[idx];
    }
}

extern "C" void kernel_launch(void* const* d_in, const int* in_sizes, int n_in,
                              void* d_out, int out_size, void* d_ws, size_t ws_size,
                              hipStream_t stream) {
  const float* mf = (const float*)d_in[0];  // (2,4096,512) f32
  const float* Wc = (const float*)d_in[1];  // (1024,512) f32
  const float* bc = (const float*)d_in[2];  // (1024,) f32
  const float* Wv = (const float*)d_in[3];  // (512,512) f32
  const float* bv = (const float*)d_in[4];  // (512,) f32
  float* out = (float*)d_out;
  unsigned short* ws = (unsigned short*)d_ws;

  const size_t elQ = (size_t)MTOT * 512;                 // per Q/V/K region (els)
  const bool kws = ws_size >= (size_t)3 * elQ * 2;       // Q+V^T+K in ws (25.2MB)

  if (kws) {
    // Abf (8.4MB) + Wbf (1.6MB) staged in the OUTPUT buffer (16.8MB, dead
    // until attn's final store; stream order serializes the hazard).
    unsigned short* Abf = (unsigned short*)out;
    unsigned short* Wbf = Abf + (size_t)MTOT * 512;
    convert_bf16<<<2048, 256, 0, stream>>>(mf, Wc, Wv, Abf);
    gemm_fast<<<1536, 256, 0, stream>>>(Abf, Wbf, bc, bv, ws);
    attn_kernel<true><<<1024, 128, 0, stream>>>(ws, mf, Wv, bv, out);
  } else {
    gemm_qvk<<<64 * 8, 256, 0, stream>>>(mf, Wc, bc, Wv, bv, ws, 8);
    attn_kernel<false><<<1024, 128, 0, stream>>>(ws, mf, Wv, bv, out);
  }
}

// Round 13
// 227.036 us; speedup vs baseline: 1.0547x; 1.0547x over previous
//
#include <hip/hip_runtime.h>

// Problem constants (B=2, S=4096, D=512, H=8, Dh=64). f32 I/O, bf16 MFMA inside.
#define MTOT 8192  // B*S

typedef __attribute__((ext_vector_type(8))) short bf16x8;
typedef __attribute__((ext_vector_type(4))) float f32x4;

// Native exp2 via builtin ONLY (round-2 lesson: inline-asm v_exp_f32 bypasses
// the compiler's MFMA/trans hazard handling -> silent corruption).
#if __has_builtin(__builtin_amdgcn_exp2f)
#define EXP2F __builtin_amdgcn_exp2f
#else
#define EXP2F exp2f
#endif

#define SC 0.18033688011112042f  // (1/8) * log2(e), folded into K
#define LDP 72                   // LDS row stride (el) for old gemm / attn P
#define CTS 136                  // epilogue C-tile stride (el), V-transpose
#define CTQ 72                   // epilogue C-tile stride (el), Q/K direct

// Truncation f32->bf16 (1 VALU). Error budget ample (0.031 vs 0.099 thresh).
static __device__ __forceinline__ unsigned short tb(float f) {
  union { float f; unsigned int i; } x;
  x.f = f;
  return (unsigned short)(x.i >> 16);
}
static __device__ __forceinline__ unsigned int pkt(float a, float b) {
  union { float f; unsigned int i; } xa, xb;
  xa.f = a; xb.f = b;
  return (xa.i >> 16) | (xb.i & 0xFFFF0000u);
}
static __device__ __forceinline__ bf16x8 ld8f32_bf16(const float* __restrict__ p) {
  f32x4 lo = *(const f32x4*)p;
  f32x4 hi = *(const f32x4*)(p + 4);
  union { unsigned int u[4]; bf16x8 v; } r;
  r.u[0] = pkt(lo[0], lo[1]);
  r.u[1] = pkt(lo[2], lo[3]);
  r.u[2] = pkt(hi[0], hi[1]);
  r.u[3] = pkt(hi[2], hi[3]);
  return r.v;
}

// Async global->LDS, 16B per lane (dest = uniform base + lane*16).
static __device__ __forceinline__ void stage16(const unsigned short* g,
                                               unsigned short* l, int lane) {
#if __has_builtin(__builtin_amdgcn_global_load_lds)
  __builtin_amdgcn_global_load_lds(
      (const __attribute__((address_space(1))) void*)g,
      (__attribute__((address_space(3))) void*)l, 16, 0, 0);
#else
  *(uint4*)(l + lane * 8) = *(const uint4*)g;
#endif
}

// ---------------------------------------------------------------------------
// Kernel 0 (fast path): f32 -> bf16. dst = [Abf 8192x512][Wbf 1536x512]
// (Wbf rows 0..1023 = Wc, 1024..1535 = Wv). dst lives in the OUTPUT buffer
// (dead until attn's final store; stream order serializes the hazard).
// ---------------------------------------------------------------------------
__global__ __launch_bounds__(256) void convert_bf16(
    const float* __restrict__ mf,
    const float* __restrict__ Wc,
    const float* __restrict__ Wv,
    unsigned short* __restrict__ dst)
{
  const size_t NA = (size_t)MTOT * 512;
  const size_t NW = (size_t)1536 * 512;
  const size_t total = (NA + NW) / 8;
  for (size_t u = (size_t)blockIdx.x * blockDim.x + threadIdx.x; u < total;
       u += (size_t)gridDim.x * blockDim.x) {
    const size_t el = u * 8;
    const float* src;
    if (el < NA) {
      src = mf + el;
    } else {
      const size_t e2 = el - NA;
      src = (e2 < (size_t)1024 * 512) ? (Wc + e2) : (Wv + (e2 - (size_t)1024 * 512));
    }
    f32x4 lo = *(const f32x4*)src;
    f32x4 hi = *(const f32x4*)(src + 4);
    uint4 pk;
    pk.x = pkt(lo[0], lo[1]); pk.y = pkt(lo[2], lo[3]);
    pk.z = pkt(hi[0], hi[1]); pk.w = pkt(hi[2], hi[3]);
    *(uint4*)(dst + el) = pk;
  }
}

// ---------------------------------------------------------------------------
// Kernel 1 (fast path): projection GEMM (round-8 verified). 128x64 tiles ->
// 1536 blocks (6/CU by 24KB LDS), acc[4][2]=32 AGPR. DMA staging: linear LDS
// dest + XOR-pre-swizzled per-lane GLOBAL source; reads use chunk^(n&7).
// XCD-chunked block swizzle (8 tm per XCD).
// Columns (tn of 24): 0-7 Q (+bc), 8-15 V (+bc, transposed), 16-23 K (+bv,*SC).
// ---------------------------------------------------------------------------
__global__ __launch_bounds__(256) void gemm_fast(
    const unsigned short* __restrict__ Abf,
    const unsigned short* __restrict__ Wbf,
    const float* __restrict__ bc,
    const float* __restrict__ bv,
    unsigned short* __restrict__ ws)
{
  const int cpx = (int)gridDim.x >> 3;  // 192 blocks per XCD chunk
  const int bid = ((int)blockIdx.x & 7) * cpx + ((int)blockIdx.x >> 3);
  const int tn = bid % 24, tm = bid / 24;
  const int w = threadIdx.x >> 6, lane = threadIdx.x & 63;
  const int n = lane & 15, q = lane >> 4;

  __shared__ alignas(16) unsigned short smem[128 * 64 + 64 * 64];  // As|Bs 24KB; Ct overlay
  unsigned short* As = smem;              // [128][64] linear (DMA dest)
  unsigned short* Bs = smem + 128 * 64;   // [64][64] linear

  f32x4 acc[4][2] = {};
  const int rowA0 = tm * 128, colB0 = tn * 64;
  const int lrow = lane >> 3;                       // 0..7 row in 8-row group
  const int sw = ((lane & 7) ^ lrow) * 8;           // XOR-swizzled source chunk
  const unsigned short* gA = Abf + (size_t)(rowA0 + w * 32 + lrow) * 512 + sw;
  const unsigned short* gB = Wbf + (size_t)(colB0 + w * 16 + lrow) * 512 + sw;

  for (int kc = 0; kc < 512; kc += 64) {
    // A: wave w rows [w*32, w*32+32); B: rows [w*16, w*16+16)
#pragma unroll
    for (int rr = 0; rr < 4; ++rr)
      stage16(gA + (size_t)rr * 8 * 512 + kc, As + (w * 32 + rr * 8) * 64, lane);
#pragma unroll
    for (int rr = 0; rr < 2; ++rr)
      stage16(gB + (size_t)rr * 8 * 512 + kc, Bs + (w * 16 + rr * 8) * 64, lane);
    __syncthreads();   // vmcnt(0) drain + barrier: tiles valid
#pragma unroll
    for (int ks = 0; ks < 2; ++ks) {
      const int ch = ((ks * 4 + q) ^ (n & 7)) * 8;  // swizzled read chunk
      bf16x8 a[4], b[2];
#pragma unroll
      for (int si = 0; si < 4; ++si)
        a[si] = *(const bf16x8*)(&As[((w >> 1) * 64 + si * 16 + n) * 64 + ch]);
#pragma unroll
      for (int sj = 0; sj < 2; ++sj)
        b[sj] = *(const bf16x8*)(&Bs[((w & 1) * 32 + sj * 16 + n) * 64 + ch]);
#pragma unroll
      for (int si = 0; si < 4; ++si)
#pragma unroll
        for (int sj = 0; sj < 2; ++sj)
          acc[si][sj] = __builtin_amdgcn_mfma_f32_16x16x32_bf16(a[si], b[sj], acc[si][sj], 0, 0, 0);
    }
    __syncthreads();   // all reads done before next stage overwrites
  }

  // ---- epilogue: LDS transpose (Ct overlays As/Bs) then coalesced stores ----
  unsigned short* Ct = smem;
  const bool isV = (tn >= 8 && tn < 16);
  const int rl0 = (w >> 1) * 64, cl0 = (w & 1) * 32;

  if (!isV) {
    const bool isK = (tn >= 16);
#pragma unroll
    for (int sj = 0; sj < 2; ++sj) {
      const int c = colB0 + cl0 + sj * 16 + n;      // full output column
      const float bias = isK ? bv[c - 1024] : bc[c];
#pragma unroll
      for (int si = 0; si < 4; ++si)
#pragma unroll
        for (int r = 0; r < 4; ++r) {
          float v = acc[si][sj][r] + bias;
          if (isK) v *= SC;
          Ct[(rl0 + si * 16 + q * 4 + r) * CTQ + cl0 + sj * 16 + n] = tb(v);
        }
    }
  } else {
#pragma unroll
    for (int sj = 0; sj < 2; ++sj) {
      const float bias = bc[colB0 + cl0 + sj * 16 + n];
#pragma unroll
      for (int si = 0; si < 4; ++si) {
        uint2 pk;
        pk.x = pkt(acc[si][sj][0] + bias, acc[si][sj][1] + bias);
        pk.y = pkt(acc[si][sj][2] + bias, acc[si][sj][3] + bias);
        *(uint2*)(&Ct[(cl0 + sj * 16 + n) * CTS + rl0 + si * 16 + q * 4]) = pk;
      }
    }
  }
  __syncthreads();

  if (!isV) {
    // Ct is [128][CTQ=72]; tile 128 rows x 64 cols
    const int rk = threadIdx.x & 7, rr2 = threadIdx.x >> 3;
#pragma unroll
    for (int rp = 0; rp < 4; ++rp) {
      const int row = rp * 32 + rr2;
      const int col = rk * 8;
      bf16x8 v = *(const bf16x8*)(&Ct[row * CTQ + col]);
      const int srow = rowA0 + row;
      const int bb = srow >> 12, ss = srow & 4095;
      const int cg = colB0 + col;
      const int cl = (cg >= 1024) ? (cg - 1024) : cg;   // K maps to [0,512)
      const int hh = cl >> 6, dh0 = cl & 63;
      unsigned short* base = (cg >= 1024) ? (ws + (size_t)2 * MTOT * 512) : ws;
      *(bf16x8*)(base + ((size_t)((bb * 8 + hh) * 4096 + ss)) * 64 + dh0) = v;
    }
  } else {
    // Ct is [64][CTS=136]; transposed tile 64 ch-rows x 128 s-cols
    const int rk = threadIdx.x & 15, rr2 = threadIdx.x >> 4;
#pragma unroll
    for (int rp = 0; rp < 4; ++rp) {
      const int row = rp * 16 + rr2;
      const int col = rk * 8;
      bf16x8 v = *(const bf16x8*)(&Ct[row * CTS + col]);
      const int cv = (tn - 8) * 64 + row;               // channel [0,512)
      const int hh = cv >> 6, dh0 = cv & 63;
      const int sg = rowA0 + col;
      const int bb = sg >> 12, ss = sg & 4095;
      *(bf16x8*)(ws + (size_t)MTOT * 512 +
                 ((size_t)((bb * 8 + hh) * 64 + dh0)) * 4096 + ss) = v;
    }
  }
}

// ---------------------------------------------------------------------------
// Kernel 1 (fallback, ws-limited): original VALU-staged projection GEMM.
// ---------------------------------------------------------------------------
__global__ __launch_bounds__(256) void gemm_qvk(
    const float* __restrict__ mf,
    const float* __restrict__ Wc,
    const float* __restrict__ bc,
    const float* __restrict__ Wv,
    const float* __restrict__ bv,
    unsigned short* __restrict__ ws,
    int nct)
{
  const int cpx = (int)gridDim.x >> 3;
  const int bid = ((int)blockIdx.x & 7) * cpx + ((int)blockIdx.x >> 3);
  const int tn = bid % nct, tm = bid / nct;
  const int w = threadIdx.x >> 6, lane = threadIdx.x & 63;
  const int n = lane & 15, q = lane >> 4;

  __shared__ alignas(16) unsigned short smem[2 * 128 * LDP];
  unsigned short* As = smem;
  unsigned short* Bs = smem + 128 * LDP;

  f32x4 acc[4][4] = {};
  const int rowA0 = tm * 128, colB0 = tn * 128;
  const int sr = threadIdx.x >> 4;
  const int sc = (threadIdx.x & 15) * 4;

  for (int kc = 0; kc < 512; kc += 64) {
    __syncthreads();
#pragma unroll
    for (int rr = 0; rr < 8; ++rr) {
      const int row = rr * 16 + sr;
      f32x4 av = *(const f32x4*)(mf + (size_t)(rowA0 + row) * 512 + kc + sc);
      uint2 ap; ap.x = pkt(av[0], av[1]); ap.y = pkt(av[2], av[3]);
      *(uint2*)(&As[row * LDP + sc]) = ap;
      const int c = colB0 + row;
      const float* bsrc = (c < 1024) ? (Wc + (size_t)c * 512)
                                     : (Wv + (size_t)(c - 1024) * 512);
      f32x4 bvx = *(const f32x4*)(bsrc + kc + sc);
      uint2 bp; bp.x = pkt(bvx[0], bvx[1]); bp.y = pkt(bvx[2], bvx[3]);
      *(uint2*)(&Bs[row * LDP + sc]) = bp;
    }
    __syncthreads();
#pragma unroll
    for (int ks = 0; ks < 2; ++ks) {
      bf16x8 a[4], b[4];
#pragma unroll
      for (int si = 0; si < 4; ++si)
        a[si] = *(const bf16x8*)(&As[((w >> 1) * 64 + si * 16 + n) * LDP + ks * 32 + q * 8]);
#pragma unroll
      for (int sj = 0; sj < 4; ++sj)
        b[sj] = *(const bf16x8*)(&Bs[((w & 1) * 64 + sj * 16 + n) * LDP + ks * 32 + q * 8]);
#pragma unroll
      for (int si = 0; si < 4; ++si)
#pragma unroll
        for (int sj = 0; sj < 4; ++sj)
          acc[si][sj] = __builtin_amdgcn_mfma_f32_16x16x32_bf16(a[si], b[sj], acc[si][sj], 0, 0, 0);
    }
  }

  __syncthreads();
  unsigned short* Ct = smem;
  const bool isV = (tn >= 4 && tn < 8);
  const int rl0 = (w >> 1) * 64, cl0 = (w & 1) * 64;

  if (!isV) {
    const bool isK = (tn >= 8);
#pragma unroll
    for (int sj = 0; sj < 4; ++sj) {
      const int c = colB0 + cl0 + sj * 16 + n;
      const float bias = isK ? bv[c - 1024] : bc[c];
#pragma unroll
      for (int si = 0; si < 4; ++si)
#pragma unroll
        for (int r = 0; r < 4; ++r) {
          float v = acc[si][sj][r] + bias;
          if (isK) v *= SC;
          Ct[(rl0 + si * 16 + q * 4 + r) * CTS + cl0 + sj * 16 + n] = tb(v);
        }
    }
  } else {
#pragma unroll
    for (int sj = 0; sj < 4; ++sj) {
      const float bias = bc[colB0 + cl0 + sj * 16 + n];
#pragma unroll
      for (int si = 0; si < 4; ++si) {
        uint2 pk;
        pk.x = pkt(acc[si][sj][0] + bias, acc[si][sj][1] + bias);
        pk.y = pkt(acc[si][sj][2] + bias, acc[si][sj][3] + bias);
        *(uint2*)(&Ct[(cl0 + sj * 16 + n) * CTS + rl0 + si * 16 + q * 4]) = pk;
      }
    }
  }
  __syncthreads();

  const int rk = threadIdx.x & 7, rr2 = threadIdx.x >> 3;
#pragma unroll
  for (int rp = 0; rp < 4; ++rp) {
    const int row = rp * 32 + rr2;
#pragma unroll
    for (int ch = 0; ch < 2; ++ch) {
      const int col = ch * 64 + rk * 8;
      bf16x8 v = *(const bf16x8*)(&Ct[row * CTS + col]);
      if (!isV) {
        const int srow = rowA0 + row;
        const int bb = srow >> 12, ss = srow & 4095;
        const int cg = colB0 + col;
        const int cl = (cg >= 1024) ? (cg - 1024) : cg;
        const int hh = cl >> 6, dh0 = cl & 63;
        unsigned short* base = (cg >= 1024) ? (ws + (size_t)2 * MTOT * 512) : ws;
        *(bf16x8*)(base + ((size_t)((bb * 8 + hh) * 4096 + ss)) * 64 + dh0) = v;
      } else {
        const int cv = (tn - 4) * 128 + row;
        const int hh = cv >> 6, dh0 = cv & 63;
        const int sg = rowA0 + col;
        const int bb = sg >> 12, ss = sg & 4095;
        *(bf16x8*)(ws + (size_t)MTOT * 512 +
                   ((size_t)((bb * 8 + hh) * 64 + dh0)) * 4096 + ss) = v;
      }
    }
  }
}

// ---------------------------------------------------------------------------
// Kernel 2: flash attention (round-10 state -- empirical best, 147.3us).
// 2 waves/block, 64 i-rows, j-split; per-iter: pipelined QK+exp (c ping-pong),
// batched P-stores, ONE lgkm drain, batched PV (32 MFMAs). Structure is at
// its latency floor for 2 waves/SIMD: occupancy^ (r1/r5), drain scheduling
// (r3/r10), setprio (r11), and LDS-transpose elimination via 32x32+shfl (r12)
// were all null or negative. Register-limited: 112 VGPR + 64 AGPR = 176;
// do NOT force higher occupancy via launch_bounds (r5: 7.6x regression).
// ---------------------------------------------------------------------------
template <bool KWS>
__global__ __launch_bounds__(128, 2) void attn_kernel(
    const unsigned short* __restrict__ qvws,
    const float* __restrict__ mf,
    const float* __restrict__ Wv,
    const float* __restrict__ bv,
    float* __restrict__ out)
{
  const int bid = blockIdx.x;
  const int bh = ((bid & 7) << 1) | ((bid >> 3) & 1);  // XCD-local bh pairing
  const int ib = bid >> 4;
  const int b_ = bh >> 3, h = bh & 7;
  const int w = threadIdx.x >> 6, lane = threadIdx.x & 63;
  const int n = lane & 15, q = lane >> 4;
  const int i0 = ib * 64;

  __shared__ alignas(16) unsigned short PK[2][64 * LDP];
  __shared__ float lbuf[2][64];

  const unsigned short* Qb = qvws + (size_t)(bh * 4096) * 64;
  const unsigned short* Vb = qvws + (size_t)MTOT * 512 + (size_t)(bh * 64) * 4096;

  bf16x8 aK[4][2];
  if (KWS) {
    const unsigned short* Kb = qvws + (size_t)2 * MTOT * 512 + (size_t)(bh * 4096) * 64;
#pragma unroll
    for (int sub = 0; sub < 4; ++sub)
#pragma unroll
      for (int s = 0; s < 2; ++s)
        aK[sub][s] = *(const bf16x8*)(Kb + (size_t)(i0 + sub * 16 + n) * 64 + s * 32 + q * 8);
  } else {
    f32x4 ka[2][4] = {};
    for (int kk = 0; kk < 512; kk += 32) {
      bf16x8 a0 = ld8f32_bf16(mf + (size_t)(b_ * 4096 + i0 + (2 * w + 0) * 16 + n) * 512 + kk + q * 8);
      bf16x8 a1 = ld8f32_bf16(mf + (size_t)(b_ * 4096 + i0 + (2 * w + 1) * 16 + n) * 512 + kk + q * 8);
#pragma unroll
      for (int t = 0; t < 4; ++t) {
        bf16x8 bw = ld8f32_bf16(Wv + (size_t)(h * 64 + t * 16 + n) * 512 + kk + q * 8);
        ka[0][t] = __builtin_amdgcn_mfma_f32_16x16x32_bf16(a0, bw, ka[0][t], 0, 0, 0);
        ka[1][t] = __builtin_amdgcn_mfma_f32_16x16x32_bf16(a1, bw, ka[1][t], 0, 0, 0);
      }
    }
#pragma unroll
    for (int sl = 0; sl < 2; ++sl)
#pragma unroll
      for (int t = 0; t < 4; ++t) {
        const float bias = bv[h * 64 + t * 16 + n];
#pragma unroll
        for (int r = 0; r < 4; ++r)
          PK[0][((2 * w + sl) * 16 + q * 4 + r) * LDP + t * 16 + n] =
              tb((ka[sl][t][r] + bias) * SC);
      }
    __syncthreads();
#pragma unroll
    for (int sub = 0; sub < 4; ++sub)
#pragma unroll
      for (int s = 0; s < 2; ++s)
        aK[sub][s] = *(const bf16x8*)(&PK[0][(sub * 16 + n) * LDP + s * 32 + q * 8]);
    __syncthreads();
  }

  f32x4 o[4][4] = {};
  float lsc[4] = {0.0f, 0.0f, 0.0f, 0.0f};
  unsigned short* Pw = &PK[w][0];
  const int jbase = w * 2048;

  bf16x8 bq[4][2], bvv[4][2];
#pragma unroll
  for (int jt = 0; jt < 4; ++jt)
#pragma unroll
    for (int s = 0; s < 2; ++s)
      bq[jt][s] = *(const bf16x8*)(Qb + (size_t)(jbase + jt * 16 + n) * 64 + s * 32 + q * 8);
#pragma unroll
  for (int t = 0; t < 4; ++t)
#pragma unroll
    for (int s = 0; s < 2; ++s)
      bvv[t][s] = *(const bf16x8*)(Vb + (size_t)(t * 16 + n) * 4096 + jbase + s * 32 + q * 8);

  for (int it = 0; it < 32; ++it) {
    const int j1 = jbase + ((it + 1) & 31) * 64;

    f32x4 c[2][4];
#pragma unroll
    for (int jt = 0; jt < 4; ++jt) {
      f32x4 z = {};
      z = __builtin_amdgcn_mfma_f32_16x16x32_bf16(bq[jt][0], aK[0][0], z, 0, 0, 0);
      z = __builtin_amdgcn_mfma_f32_16x16x32_bf16(bq[jt][1], aK[0][1], z, 0, 0, 0);
      c[0][jt] = z;
    }

    // Phase 1: QK(sub+1) pipelined ahead of exp(sub); P stores per sub.
#pragma unroll
    for (int sub = 0; sub < 4; ++sub) {
      const int cur = sub & 1, nxt = cur ^ 1;
      if (sub < 3) {
#pragma unroll
        for (int jt = 0; jt < 4; ++jt) {
          f32x4 z = {};
          z = __builtin_amdgcn_mfma_f32_16x16x32_bf16(bq[jt][0], aK[sub + 1][0], z, 0, 0, 0);
          z = __builtin_amdgcn_mfma_f32_16x16x32_bf16(bq[jt][1], aK[sub + 1][1], z, 0, 0, 0);
          c[nxt][jt] = z;
        }
      }
      if (sub == 2) {
#pragma unroll
        for (int jt = 0; jt < 4; ++jt)
#pragma unroll
          for (int s = 0; s < 2; ++s)
            bq[jt][s] = *(const bf16x8*)(Qb + (size_t)(j1 + jt * 16 + n) * 64 + s * 32 + q * 8);
      }

#pragma unroll
      for (int jt = 0; jt < 4; ++jt) {
        float e0 = EXP2F(c[cur][jt][0]), e1 = EXP2F(c[cur][jt][1]);
        float e2 = EXP2F(c[cur][jt][2]), e3 = EXP2F(c[cur][jt][3]);
        lsc[sub] += (e0 + e1) + (e2 + e3);
        uint2 pk;
        pk.x = pkt(e0, e1);
        pk.y = pkt(e2, e3);
        *(uint2*)(Pw + (sub * 16 + n) * LDP + jt * 16 + q * 4) = pk;
      }
    }

    // Single drain: sub0-2 stores retired under later subs' compute.
    asm volatile("s_waitcnt lgkmcnt(0)" ::: "memory");

    // Phase 2: batched PV (32 MFMAs, 8 ds_read_b128).
#pragma unroll
    for (int sub = 0; sub < 4; ++sub) {
#pragma unroll
      for (int s = 0; s < 2; ++s) {
        bf16x8 pa = *(const bf16x8*)(Pw + (sub * 16 + n) * LDP + s * 32 + q * 8);
#pragma unroll
        for (int t = 0; t < 4; ++t)
          o[sub][t] = __builtin_amdgcn_mfma_f32_16x16x32_bf16(pa, bvv[t][s], o[sub][t], 0, 0, 0);
      }
    }

#pragma unroll
    for (int t = 0; t < 4; ++t)
#pragma unroll
      for (int s = 0; s < 2; ++s)
        bvv[t][s] = *(const bf16x8*)(Vb + (size_t)(t * 16 + n) * 4096 + j1 + s * 32 + q * 8);
  }

  float lw[4];
#pragma unroll
  for (int sub = 0; sub < 4; ++sub) {
    float v = lsc[sub];
    v += __shfl_xor(v, 16, 64);
    v += __shfl_xor(v, 32, 64);
    lw[sub] = v;
  }

  __syncthreads();
  float* mO = (float*)&PK[0][0];
  const int ebase = (w == 0) ? 0 : 32;
  const int rbase = (w == 0) ? 32 : 0;
  const int esub0 = (w == 0) ? 2 : 0;
  const int ksub0 = (w == 0) ? 0 : 2;
#pragma unroll
  for (int sl = 0; sl < 2; ++sl) {
    const int sub = esub0 + sl;
#pragma unroll
    for (int t = 0; t < 4; ++t)
#pragma unroll
      for (int r = 0; r < 4; ++r)
        mO[(ebase + sl * 16 + q * 4 + r) * 68 + t * 16 + n] = o[sub][t][r];
  }
  if (lane < 16) {
#pragma unroll
    for (int sub = 0; sub < 4; ++sub)
      lbuf[w][sub * 16 + lane] = lw[sub];
  }
  __syncthreads();
#pragma unroll
  for (int sl = 0; sl < 2; ++sl) {
    const int sub = ksub0 + sl;
    float li[4];
#pragma unroll
    for (int r = 0; r < 4; ++r) {
      const int il = sub * 16 + q * 4 + r;
      li[r] = 1.0f / (lbuf[0][il] + lbuf[1][il]);
    }
#pragma unroll
    for (int t = 0; t < 4; ++t) {
#pragma unroll
      for (int r = 0; r < 4; ++r) {
        const int i = i0 + sub * 16 + q * 4 + r;
        const int dh = t * 16 + n;
        const size_t idx = (size_t)(b_ * 4096 + i) * 512 + h * 64 + dh;
        out[idx] = (o[sub][t][r] + mO[(rbase + sl * 16 + q * 4 + r) * 68 + t * 16 + n]) * li[r]
                   + mf[idx];
      }
    }
  }
}

extern "C" void kernel_launch(void* const* d_in, const int* in_sizes, int n_in,
                              void* d_out, int out_size, void* d_ws, size_t ws_size,
                              hipStream_t stream) {
  const float* mf = (const float*)d_in[0];  // (2,4096,512) f32
  const float* Wc = (const float*)d_in[1];  // (1024,512) f32
  const float* bc = (const float*)d_in[2];  // (1024,) f32
  const float* Wv = (const float*)d_in[3];  // (512,512) f32
  const float* bv = (const float*)d_in[4];  // (512,) f32
  float* out = (float*)d_out;
  unsigned short* ws = (unsigned short*)d_ws;

  const size_t elQ = (size_t)MTOT * 512;                 // per Q/V/K region (els)
  const bool kws = ws_size >= (size_t)3 * elQ * 2;       // Q+V^T+K in ws (25.2MB)

  if (kws) {
    // Abf (8.4MB) + Wbf (1.6MB) staged in the OUTPUT buffer (16.8MB, dead
    // until attn's final store; stream order serializes the hazard).
    unsigned short* Abf = (unsigned short*)out;
    unsigned short* Wbf = Abf + (size_t)MTOT * 512;
    convert_bf16<<<2048, 256, 0, stream>>>(mf, Wc, Wv, Abf);
    gemm_fast<<<1536, 256, 0, stream>>>(Abf, Wbf, bc, bv, ws);
    attn_kernel<true><<<1024, 128, 0, stream>>>(ws, mf, Wv, bv, out);
  } else {
    gemm_qvk<<<64 * 8, 256, 0, stream>>>(mf, Wc, bc, Wv, bv, ws, 8);
    attn_kernel<false><<<1024, 128, 0, stream>>>(ws, mf, Wv, bv, out);
  }
}